// Round 1
// baseline (402.978 us; speedup 1.0000x reference)
//
#include <hip/hip_runtime.h>

// Problem constants (from reference): B=1024, D=128, N_LANGS=8000
#define NB    1024
#define ND    128
#define NLANG 8000

#define TILE    32   // 32x32 pair tile per block
#define NPAIR   16   // row-pairs per tile
#define PSTRIDE 65   // float4 stride per row-pair: 64 data f4 + 1 pad f4
                     // -> per-lane ds_read_b128 start banks = 4*tx mod 32 (2-way, free)

__global__ void lesl_init(float* ws) {
    ws[0] = 0.0f;  // numerator sum
    ws[1] = 0.0f;  // mask count
}

__global__ __launch_bounds__(256) void lesl_main(
    const int*   __restrict__ ids,
    const float* __restrict__ emb,
    const float* __restrict__ md,
    float*       __restrict__ ws)
{
    // Layout: sX[pair*PSTRIDE + 2*c + w] holds float4 c of row (2*pair + w)
    __shared__ float4 sI[NPAIR * PSTRIDE];
    __shared__ float4 sJ[NPAIR * PSTRIDE];

    const int tid = threadIdx.x;
    const int bi  = blockIdx.x & 31;
    const int bj  = blockIdx.x >> 5;
    const int i0  = bi * TILE;
    const int j0  = bj * TILE;

    const float4* embv = (const float4*)emb;   // 32 float4 per embedding row

    // Cooperative stage: 32 rows x 32 f4 per tile, 256 threads -> 4 f4 each per tile
    for (int k = tid; k < TILE * (ND / 4); k += 256) {
        const int r   = k >> 5;        // row within tile
        const int c   = k & 31;        // float4 column
        const int dst = (r >> 1) * PSTRIDE + (c << 1) + (r & 1);
        sI[dst] = embv[(size_t)(i0 + r) * (ND / 4) + c];
        sJ[dst] = embv[(size_t)(j0 + r) * (ND / 4) + c];
    }
    __syncthreads();

    const int tx = tid & 15;   // j row-pair index
    const int ty = tid >> 4;   // i row-pair index
    const float4* pI = &sI[ty * PSTRIDE];
    const float4* pJ = &sJ[tx * PSTRIDE];

    float4 a00 = {0,0,0,0}, a01 = {0,0,0,0}, a10 = {0,0,0,0}, a11 = {0,0,0,0};

#define ACC(A, X, Y)                              \
    A.x += __builtin_fabsf(X.x - Y.x);            \
    A.y += __builtin_fabsf(X.y - Y.y);            \
    A.z += __builtin_fabsf(X.z - Y.z);            \
    A.w += __builtin_fabsf(X.w - Y.w);

    #pragma unroll 4
    for (int c = 0; c < 32; ++c) {
        const float4 x0 = pI[2 * c];
        const float4 x1 = pI[2 * c + 1];
        const float4 y0 = pJ[2 * c];
        const float4 y1 = pJ[2 * c + 1];
        ACC(a00, x0, y0);
        ACC(a01, x0, y1);
        ACC(a10, x1, y0);
        ACC(a11, x1, y1);
    }
#undef ACC

    const int i_a = i0 + (ty << 1);
    const int j_a = j0 + (tx << 1);
    const int idi0 = ids[i_a];
    const int idi1 = ids[i_a + 1];
    const int idj0 = ids[j_a];
    const int idj1 = ids[j_a + 1];

    float s = 0.0f, cnt = 0.0f;

    auto contrib = [&](const float4& A, int ia, int ib) {
        const float sad  = (A.x + A.y) + (A.z + A.w);
        const float m    = md[(size_t)ia * NLANG + ib];
        const float diff = __builtin_fabsf(sad * 0.0078125f - m);  // /128 exact
        if (ia != ib) { s += diff; cnt += 1.0f; }
    };
    contrib(a00, idi0, idj0);
    contrib(a01, idi0, idj1);
    contrib(a10, idi1, idj0);
    contrib(a11, idi1, idj1);

    // wave64 shuffle reduction, one atomic pair per wave
    #pragma unroll
    for (int off = 32; off > 0; off >>= 1) {
        s   += __shfl_down(s,   off, 64);
        cnt += __shfl_down(cnt, off, 64);
    }
    if ((tid & 63) == 0) {
        atomicAdd(&ws[0], s);
        atomicAdd(&ws[1], cnt);
    }
}

__global__ void lesl_fin(const float* __restrict__ ws, float* __restrict__ out) {
    out[0] = ws[0] / ws[1];
}

extern "C" void kernel_launch(void* const* d_in, const int* in_sizes, int n_in,
                              void* d_out, int out_size, void* d_ws, size_t ws_size,
                              hipStream_t stream) {
    const int*   ids = (const int*)d_in[0];
    const float* emb = (const float*)d_in[1];
    const float* md  = (const float*)d_in[2];
    float* out = (float*)d_out;
    float* ws  = (float*)d_ws;

    lesl_init<<<dim3(1), dim3(1), 0, stream>>>(ws);
    lesl_main<<<dim3((NB / TILE) * (NB / TILE)), dim3(256), 0, stream>>>(ids, emb, md, ws);
    lesl_fin<<<dim3(1), dim3(1), 0, stream>>>(ws, out);
}

// Round 2
// 307.408 us; speedup vs baseline: 1.3109x; 1.3109x over previous
//
#include <hip/hip_runtime.h>

// Problem constants (from reference): B=1024, D=128, N_LANGS=8000
#define NB    1024
#define ND    128
#define NLANG 8000

#define TILE    32   // 32x32 pair tile per block
#define NPAIR   16   // row-pairs per tile
#define PSTRIDE 65   // float4 stride per row-pair: 64 data f4 + 1 pad f4
                     // -> per-lane ds_read_b128 start banks = 4*tx mod 32 (2-way, free)
#define NBLK  ((NB / TILE) * (NB / TILE))   // 1024 blocks

__global__ __launch_bounds__(256) void lesl_main(
    const int*   __restrict__ ids,
    const float* __restrict__ emb,
    const float* __restrict__ md,
    float*       __restrict__ partials)   // [NBLK] float2: (sum, count)
{
    __shared__ float4 sI[NPAIR * PSTRIDE];
    __shared__ float4 sJ[NPAIR * PSTRIDE];
    __shared__ float  red[8];             // cross-wave reduction (4 waves x 2)

    const int tid = threadIdx.x;
    const int bi  = blockIdx.x & 31;
    const int bj  = blockIdx.x >> 5;
    const int i0  = bi * TILE;
    const int j0  = bj * TILE;

    const int tx = tid & 15;   // j row-pair index
    const int ty = tid >> 4;   // i row-pair index

    // ---- HOIST: ids + md gathers issued FIRST so ~900cy HBM latency hides
    // under LDS staging + the 32-iter compute loop. ----
    const int i_a  = i0 + (ty << 1);
    const int j_a  = j0 + (tx << 1);
    const int idi0 = ids[i_a];
    const int idi1 = ids[i_a + 1];
    const int idj0 = ids[j_a];
    const int idj1 = ids[j_a + 1];
    const float m00 = md[(size_t)idi0 * NLANG + idj0];
    const float m01 = md[(size_t)idi0 * NLANG + idj1];
    const float m10 = md[(size_t)idi1 * NLANG + idj0];
    const float m11 = md[(size_t)idi1 * NLANG + idj1];

    // ---- Cooperative stage: 32 rows x 32 f4 per tile, 4 f4 per thread ----
    const float4* embv = (const float4*)emb;   // 32 float4 per embedding row
    for (int k = tid; k < TILE * (ND / 4); k += 256) {
        const int r   = k >> 5;        // row within tile
        const int c   = k & 31;        // float4 column
        const int dst = (r >> 1) * PSTRIDE + (c << 1) + (r & 1);
        sI[dst] = embv[(size_t)(i0 + r) * (ND / 4) + c];
        sJ[dst] = embv[(size_t)(j0 + r) * (ND / 4) + c];
    }
    __syncthreads();

    const float4* pI = &sI[ty * PSTRIDE];
    const float4* pJ = &sJ[tx * PSTRIDE];

    float4 a00 = {0,0,0,0}, a01 = {0,0,0,0}, a10 = {0,0,0,0}, a11 = {0,0,0,0};

#define ACC(A, X, Y)                              \
    A.x += __builtin_fabsf(X.x - Y.x);            \
    A.y += __builtin_fabsf(X.y - Y.y);            \
    A.z += __builtin_fabsf(X.z - Y.z);            \
    A.w += __builtin_fabsf(X.w - Y.w);

    #pragma unroll 4
    for (int c = 0; c < 32; ++c) {
        const float4 x0 = pI[2 * c];
        const float4 x1 = pI[2 * c + 1];
        const float4 y0 = pJ[2 * c];
        const float4 y1 = pJ[2 * c + 1];
        ACC(a00, x0, y0);
        ACC(a01, x0, y1);
        ACC(a10, x1, y0);
        ACC(a11, x1, y1);
    }
#undef ACC

    float s = 0.0f, cnt = 0.0f;
    auto contrib = [&](const float4& A, int ia, int ib, float m) {
        const float sad  = (A.x + A.y) + (A.z + A.w);
        const float diff = __builtin_fabsf(sad * 0.0078125f - m);  // /128 exact
        if (ia != ib) { s += diff; cnt += 1.0f; }
    };
    contrib(a00, idi0, idj0, m00);
    contrib(a01, idi0, idj1, m01);
    contrib(a10, idi1, idj0, m10);
    contrib(a11, idi1, idj1, m11);

    // ---- wave64 shuffle reduce, then 4-wave LDS reduce; one store/block ----
    #pragma unroll
    for (int off = 32; off > 0; off >>= 1) {
        s   += __shfl_down(s,   off, 64);
        cnt += __shfl_down(cnt, off, 64);
    }
    const int wid = tid >> 6;
    if ((tid & 63) == 0) { red[wid] = s; red[4 + wid] = cnt; }
    __syncthreads();
    if (tid == 0) {
        float S = red[0] + red[1] + red[2] + red[3];
        float C = red[4] + red[5] + red[6] + red[7];
        ((float2*)partials)[blockIdx.x] = make_float2(S, C);
    }
}

// Reduce 1024 (sum,count) pairs -> out[0] = S/C. One block.
__global__ __launch_bounds__(256) void lesl_reduce(
    const float* __restrict__ partials, float* __restrict__ out)
{
    __shared__ float red[8];
    const int tid = threadIdx.x;
    const float2* p = (const float2*)partials;

    float s = 0.0f, c = 0.0f;
    #pragma unroll
    for (int k = 0; k < 4; ++k) {
        const float2 v = p[tid * 4 + k];
        s += v.x; c += v.y;
    }
    #pragma unroll
    for (int off = 32; off > 0; off >>= 1) {
        s += __shfl_down(s, off, 64);
        c += __shfl_down(c, off, 64);
    }
    const int wid = tid >> 6;
    if ((tid & 63) == 0) { red[wid] = s; red[4 + wid] = c; }
    __syncthreads();
    if (tid == 0) {
        const float S = red[0] + red[1] + red[2] + red[3];
        const float C = red[4] + red[5] + red[6] + red[7];
        out[0] = S / C;
    }
}

extern "C" void kernel_launch(void* const* d_in, const int* in_sizes, int n_in,
                              void* d_out, int out_size, void* d_ws, size_t ws_size,
                              hipStream_t stream) {
    const int*   ids = (const int*)d_in[0];
    const float* emb = (const float*)d_in[1];
    const float* md  = (const float*)d_in[2];
    float* out = (float*)d_out;
    float* ws  = (float*)d_ws;   // used as float2[NBLK] partials (poison overwritten)

    lesl_main<<<dim3(NBLK), dim3(256), 0, stream>>>(ids, emb, md, ws);
    lesl_reduce<<<dim3(1), dim3(256), 0, stream>>>(ws, out);
}